// Round 7
// baseline (487.779 us; speedup 1.0000x reference)
//
#include <hip/hip_runtime.h>
#include <hip/hip_bf16.h>

typedef __bf16 bf16x8 __attribute__((ext_vector_type(8)));
typedef float f32x4 __attribute__((ext_vector_type(4)));
typedef unsigned short ushort8v __attribute__((ext_vector_type(8)));

__device__ __forceinline__ unsigned short f2bf(float f) {
    unsigned int u = __float_as_uint(f);
    u = (u + 0x7fffu + ((u >> 16) & 1u)) >> 16;
    return (unsigned short)u;
}

__device__ __forceinline__ f32x4 mfma16(bf16x8 a, bf16x8 b, f32x4 c) {
    return __builtin_amdgcn_mfma_f32_16x16x32_bf16(a, b, c, 0, 0, 0);
}

__device__ __forceinline__ void store_c(unsigned short* p, float v) { *p = f2bf(v); }
__device__ __forceinline__ void store_c(float* p, float v) { *p = v; }

// ---------------- cast f32 -> bf16 (vectorized) ----------------
__global__ __launch_bounds__(256) void cast_f32_bf16(const float* __restrict__ in,
                                                     unsigned short* __restrict__ out,
                                                     int n4) {
    int i = blockIdx.x * blockDim.x + threadIdx.x;
    if (i < n4) {
        float4 f = ((const float4*)in)[i];
        ushort4 u;
        u.x = f2bf(f.x); u.y = f2bf(f.y); u.z = f2bf(f.z); u.w = f2bf(f.w);
        ((ushort4*)out)[i] = u;
    }
}

// ---------------- V transpose: v(token,channel) -> vt(bh*128+d, s) ----------------
__global__ __launch_bounds__(256) void transpose_v(const unsigned short* __restrict__ v,
                                                   unsigned short* __restrict__ vt) {
    __shared__ unsigned short t[64][65];
    const int tid = threadIdx.x;
    const int s0 = blockIdx.x * 64;
    const int d0 = blockIdx.y * 64;
    const int bh = blockIdx.z;            // b*16+h
    const int b = bh >> 4, h = bh & 15;

#pragma unroll
    for (int i = 0; i < 2; ++i) {
        int idx = i * 256 + tid;
        int r = idx >> 3, c8 = (idx & 7) * 8;
        ushort8v d = *(const ushort8v*)(v + ((size_t)(b * 2048 + s0 + r)) * 2048 + h * 128 + d0 + c8);
#pragma unroll
        for (int j = 0; j < 8; ++j) t[r][c8 + j] = d[j];
    }
    __syncthreads();
#pragma unroll
    for (int i = 0; i < 2; ++i) {
        int idx = i * 256 + tid;
        int dr = idx >> 3, sc8 = (idx & 7) * 8;
        ushort8v o;
#pragma unroll
        for (int j = 0; j < 8; ++j) o[j] = t[sc8 + j][dr];
        *(ushort8v*)(vt + ((size_t)(bh * 128 + d0 + dr)) * 2048 + s0 + sc8) = o;
    }
}

// ---------------- pipelined GEMM: C = A (MxK) * B^T (B is NxK) ----------------
// 256x128 tile, BK=32, 8 waves (2M x 4N), 3-stage LDS ring, counted vmcnt,
// raw s_barrier (no vmcnt(0) drain in steady state). XOR-swizzled LDS:
// physical chunk p of row r holds global chunk p ^ ((r>>1)&3).
__device__ __forceinline__ void stage_tile(const unsigned short* __restrict__ A,
                                           const unsigned short* __restrict__ B,
                                           char* lAslot, char* lBslot,
                                           int row0, int col0, int kt, int K,
                                           int tid, int w) {
#pragma unroll
    for (int j = 0; j < 2; ++j) {
        int ci = j * 512 + tid;
        int r = ci >> 2, p = ci & 3;
        int c = p ^ ((r >> 1) & 3);
        size_t goff = ((size_t)(row0 + r) * K + kt + c * 8) * 2;
        __builtin_amdgcn_global_load_lds(
            (__attribute__((address_space(1))) void*)(void*)((const char*)A + goff),
            (__attribute__((address_space(3))) void*)(lAslot + (j * 512 + w * 64) * 16),
            16, 0, 0);
    }
    {
        int ci = tid;
        int r = ci >> 2, p = ci & 3;
        int c = p ^ ((r >> 1) & 3);
        size_t goff = ((size_t)(col0 + r) * K + kt + c * 8) * 2;
        __builtin_amdgcn_global_load_lds(
            (__attribute__((address_space(1))) void*)(void*)((const char*)B + goff),
            (__attribute__((address_space(3))) void*)(lBslot + (w * 64) * 16),
            16, 0, 0);
    }
}

template <typename OUT_T>
__global__ __launch_bounds__(512) void gemm_bt2(const unsigned short* __restrict__ A,
                                                const unsigned short* __restrict__ B,
                                                OUT_T* __restrict__ C,
                                                int M, int N, int K) {
    __shared__ __align__(16) unsigned short lA[3][256 * 32];  // 3 x 16KB
    __shared__ __align__(16) unsigned short lB[3][128 * 32];  // 3 x 8KB

    const int tid = threadIdx.x;          // 0..511
    const int w = tid >> 6, lane = tid & 63;
    const int wm = w >> 2, wn = w & 3;    // 2 x 4 wave grid
    const int lane16 = lane & 15, g = lane >> 4;
    const int row0 = blockIdx.y * 256, col0 = blockIdx.x * 128;
    const int NT = K >> 5;

    f32x4 acc[8][2] = {};

    // prologue: stage tiles 0,1,2 into slots 0,1,2 (3 vmem loads per thread each)
    stage_tile(A, B, (char*)lA[0], (char*)lB[0], row0, col0, 0, K, tid, w);
    stage_tile(A, B, (char*)lA[1], (char*)lB[1], row0, col0, 32, K, tid, w);
    stage_tile(A, B, (char*)lA[2], (char*)lB[2], row0, col0, 64, K, tid, w);

    int s = 0;
#pragma unroll 1
    for (int t = 0; t < NT; ++t) {
        // tile t resident once outstanding <= loads of tiles t+1, t+2
        if (t + 2 < NT)      asm volatile("s_waitcnt vmcnt(6)" ::: "memory");
        else if (t + 1 < NT) asm volatile("s_waitcnt vmcnt(3)" ::: "memory");
        else                 asm volatile("s_waitcnt vmcnt(0)" ::: "memory");
        __builtin_amdgcn_s_barrier();
        asm volatile("" ::: "memory");

        bf16x8 aF[8], bF[2];
#pragma unroll
        for (int mf = 0; mf < 8; ++mf) {
            int r = wm * 128 + mf * 16 + lane16;
            aF[mf] = *(const bf16x8*)&lA[s][r * 32 + (g ^ ((r >> 1) & 3)) * 8];
        }
#pragma unroll
        for (int nf = 0; nf < 2; ++nf) {
            int r = wn * 32 + nf * 16 + lane16;
            bF[nf] = *(const bf16x8*)&lB[s][r * 32 + (g ^ ((r >> 1) & 3)) * 8];
        }
        __builtin_amdgcn_s_setprio(1);
#pragma unroll
        for (int mf = 0; mf < 8; ++mf)
#pragma unroll
            for (int nf = 0; nf < 2; ++nf)
                acc[mf][nf] = mfma16(aF[mf], bF[nf], acc[mf][nf]);
        __builtin_amdgcn_s_setprio(0);

        asm volatile("" ::: "memory");
        __builtin_amdgcn_s_barrier();
        asm volatile("" ::: "memory");

        if (t + 3 < NT)
            stage_tile(A, B, (char*)lA[s], (char*)lB[s], row0, col0, (t + 3) * 32, K, tid, w);
        s = (s == 2) ? 0 : s + 1;
    }

#pragma unroll
    for (int mf = 0; mf < 8; ++mf) {
        int r0 = row0 + wm * 128 + mf * 16 + g * 4;
#pragma unroll
        for (int nf = 0; nf < 2; ++nf) {
            int c = col0 + wn * 32 + nf * 16 + lane16;
#pragma unroll
            for (int r = 0; r < 4; ++r)
                store_c(&C[(size_t)(r0 + r) * N + c], acc[mf][nf][r]);
        }
    }
}

// ---------------- causal flash attention ----------------
// Q,K: (B*S, 2048) bf16 (head h at cols h*128..); VT: (bh*128+d, s); O: (B*S, 2048)
// block: 4 waves, each owns 16 q-rows; KV tiles of 64.
// Work-balanced: block bx handles q-tile bx, then q-tile 31-bx (33 KV tiles total).
// lK and lVt are chunk-XOR-swizzled via pre-swizzled global_load_lds source.
__global__ __launch_bounds__(256) void attn_causal(const unsigned short* __restrict__ Q,
                                                   const unsigned short* __restrict__ K,
                                                   const unsigned short* __restrict__ VT,
                                                   unsigned short* __restrict__ O) {
    __shared__ __align__(16) unsigned short lK[64 * 128];    // swizzled content
    __shared__ __align__(16) unsigned short lVt[128 * 64];   // swizzled content (d-major)
    __shared__ __align__(16) unsigned short lP[4][16 * 80];  // per-wave P tile

    const int tid = threadIdx.x, w = tid >> 6, lane = tid & 63;
    const int lane16 = lane & 15, g = lane >> 4;
    const int bh = blockIdx.y;
    const int b = bh >> 4, h = bh & 15;
    const size_t rowBase = (size_t)b * 2048;  // b*S
    const int hoff = h * 128;
    const float scale = 0.08838834764831845f;  // 1/sqrt(128)

    for (int pass = 0; pass < 2; ++pass) {
        const int qt = pass ? (31 - (int)blockIdx.x) : (int)blockIdx.x;
        const int qt0 = qt * 64;
        const int qr0 = qt0 + w * 16;

        // Q fragments in registers (16 rows x 128 cols)
        bf16x8 qa[4];
        {
            const unsigned short* qp = Q + (rowBase + qr0 + lane16) * 2048 + hoff;
#pragma unroll
            for (int kk = 0; kk < 4; ++kk)
                qa[kk] = *(const bf16x8*)(qp + kk * 32 + g * 8);
        }

        float m_r[4], l_r[4];
        f32x4 accO[8];
#pragma unroll
        for (int r = 0; r < 4; ++r) { m_r[r] = -1e30f; l_r[r] = 0.f; }
#pragma unroll
        for (int f = 0; f < 8; ++f) accO[f] = f32x4{0.f, 0.f, 0.f, 0.f};

        const int nt = qt + 1;

        for (int t = 0; t < nt; ++t) {
            const int kv0 = t * 64;
            __syncthreads();
            // stage K tile (64 rows x 128 cols): LDS chunk (row, c) holds global chunk c^(row&7)
#pragma unroll
            for (int i = 0; i < 4; ++i) {
                int ci = (w * 4 + i) * 64 + lane;   // LDS 16B chunk position
                int krow = ci >> 4;                 // 16 chunks per 256B row
                int kcolb = ((ci & 15) ^ (krow & 7)) * 16;
                size_t goff = ((rowBase + kv0 + krow) * 2048 + hoff) * 2 + kcolb;
                __builtin_amdgcn_global_load_lds(
                    (__attribute__((address_space(1))) void*)(void*)((const char*)K + goff),
                    (__attribute__((address_space(3))) void*)((char*)lK + (w * 4 + i) * 1024),
                    16, 0, 0);
            }
            // stage Vt tile (128 d-rows x 64 kv cols): 8 chunks/row, chunk c holds c^(d&7)
#pragma unroll
            for (int i = 0; i < 4; ++i) {
                int ci = (w * 4 + i) * 64 + lane;   // LDS 16B chunk position (0..1023)
                int drow = ci >> 3;                 // 8 chunks per 128B row
                int slot = (ci & 7) ^ (drow & 7);
                size_t goff = ((size_t)(bh * 128 + drow) * 2048 + kv0 + slot * 8) * 2;
                __builtin_amdgcn_global_load_lds(
                    (__attribute__((address_space(1))) void*)(void*)((const char*)VT + goff),
                    (__attribute__((address_space(3))) void*)((char*)lVt + (w * 4 + i) * 1024),
                    16, 0, 0);
            }
            __syncthreads();

            // scores S = Q*K^T (16 x 64), in f32 regs p[n16][r]
            float p[4][4];
#pragma unroll
            for (int n = 0; n < 4; ++n) {
                f32x4 sc = {0.f, 0.f, 0.f, 0.f};
                int row = n * 16 + lane16;
#pragma unroll
                for (int kk = 0; kk < 4; ++kk) {
                    int sw = (kk * 4 + g) ^ (row & 7);   // read-side swizzle
                    bf16x8 kb = *(const bf16x8*)&lK[row * 128 + sw * 8];
                    sc = mfma16(qa[kk], kb, sc);
                }
#pragma unroll
                for (int r = 0; r < 4; ++r) p[n][r] = sc[r] * scale;
            }
            if (t == nt - 1) {  // only the diagonal tile needs masking
#pragma unroll
                for (int n = 0; n < 4; ++n)
#pragma unroll
                    for (int r = 0; r < 4; ++r) {
                        int qi = qr0 + g * 4 + r, ki = kv0 + n * 16 + lane16;
                        if (ki > qi) p[n][r] = -1e30f;
                    }
            }
            // online softmax; row (g*4+r) lives across the 16 lanes of group g
#pragma unroll
            for (int r = 0; r < 4; ++r) {
                float rm = fmaxf(fmaxf(p[0][r], p[1][r]), fmaxf(p[2][r], p[3][r]));
#pragma unroll
                for (int off = 1; off < 16; off <<= 1)
                    rm = fmaxf(rm, __shfl_xor(rm, off, 64));
                float mn = fmaxf(m_r[r], rm);
                float fac = __expf(m_r[r] - mn);
                float rs = 0.f;
#pragma unroll
                for (int n = 0; n < 4; ++n) { p[n][r] = __expf(p[n][r] - mn); rs += p[n][r]; }
#pragma unroll
                for (int off = 1; off < 16; off <<= 1)
                    rs += __shfl_xor(rs, off, 64);
                l_r[r] = l_r[r] * fac + rs;
                m_r[r] = mn;
#pragma unroll
                for (int f = 0; f < 8; ++f) accO[f][r] *= fac;
            }
            // P -> LDS (bf16), then read back as A-fragments
#pragma unroll
            for (int n = 0; n < 4; ++n)
#pragma unroll
                for (int r = 0; r < 4; ++r)
                    lP[w][(g * 4 + r) * 80 + n * 16 + lane16] = f2bf(p[n][r]);
            asm volatile("s_waitcnt lgkmcnt(0)" ::: "memory");
            // PV: out += P (16x64) * V (64x128); V^T fragments from swizzled lVt
#pragma unroll
            for (int kk2 = 0; kk2 < 2; ++kk2) {
                bf16x8 pa = *(const bf16x8*)&lP[w][lane16 * 80 + kk2 * 32 + g * 8];
#pragma unroll
                for (int f = 0; f < 8; ++f) {
                    int row = f * 16 + lane16;
                    int slot = (kk2 * 4 + g) ^ (row & 7);
                    bf16x8 vb = *(const bf16x8*)&lVt[row * 64 + slot * 8];
                    accO[f] = mfma16(pa, vb, accO[f]);
                }
            }
        }

#pragma unroll
        for (int f = 0; f < 8; ++f)
#pragma unroll
            for (int r = 0; r < 4; ++r) {
                float ov = accO[f][r] / l_r[r];
                O[(rowBase + qr0 + g * 4 + r) * 2048 + hoff + f * 16 + lane16] = f2bf(ov);
            }
    }
}

// ---------------- launch ----------------
extern "C" void kernel_launch(void* const* d_in, const int* in_sizes, int n_in,
                              void* d_out, int out_size, void* d_ws, size_t ws_size,
                              hipStream_t stream) {
    const float* x  = (const float*)d_in[0];
    // d_in[1] = causal mask (static triu(k=1)) — applied analytically
    const float* Wq = (const float*)d_in[2];
    const float* Wk = (const float*)d_in[3];
    const float* Wv = (const float*)d_in[4];
    const float* Wo = (const float*)d_in[5];
    float* out = (float*)d_out;

    char* ws = (char*)d_ws;
    unsigned short* xb = (unsigned short*)(ws);                    // 16MB; x bf16, later vt
    unsigned short* q  = (unsigned short*)(ws + (size_t)(16u << 20));
    unsigned short* k  = (unsigned short*)(ws + (size_t)(32u << 20));
    unsigned short* v  = (unsigned short*)(ws + (size_t)(48u << 20)); // v bf16, later attn O
    unsigned short* wb = (unsigned short*)(ws + (size_t)(64u << 20)); // 8MB weight buf
    unsigned short* vt = xb;   // vt reuses xb region (x dead after QKV gemms)
    unsigned short* o  = v;    // attn output reuses v region (v dead after transpose)

    const int M = 4096, D = 2048;
    dim3 gg(D / 128, M / 256);  // (16, 16) = 256 blocks, uniform

    cast_f32_bf16<<<(M * D / 4) / 256, 256, 0, stream>>>(x, xb, M * D / 4);

    cast_f32_bf16<<<(D * D / 4) / 256, 256, 0, stream>>>(Wq, wb, D * D / 4);
    gemm_bt2<unsigned short><<<gg, 512, 0, stream>>>(xb, wb, q, M, D, D);
    cast_f32_bf16<<<(D * D / 4) / 256, 256, 0, stream>>>(Wk, wb, D * D / 4);
    gemm_bt2<unsigned short><<<gg, 512, 0, stream>>>(xb, wb, k, M, D, D);
    cast_f32_bf16<<<(D * D / 4) / 256, 256, 0, stream>>>(Wv, wb, D * D / 4);
    gemm_bt2<unsigned short><<<gg, 512, 0, stream>>>(xb, wb, v, M, D, D);

    transpose_v<<<dim3(32, 2, 32), 256, 0, stream>>>(v, vt);

    attn_causal<<<dim3(16, 32), 256, 0, stream>>>(q, k, vt, o);

    cast_f32_bf16<<<(D * D / 4) / 256, 256, 0, stream>>>(Wo, wb, D * D / 4);
    gemm_bt2<float><<<gg, 512, 0, stream>>>(o, wb, out, M, D, D);
}

// Round 9
// 445.635 us; speedup vs baseline: 1.0946x; 1.0946x over previous
//
#include <hip/hip_runtime.h>
#include <hip/hip_bf16.h>

typedef __bf16 bf16x8 __attribute__((ext_vector_type(8)));
typedef float f32x4 __attribute__((ext_vector_type(4)));
typedef unsigned short ushort8v __attribute__((ext_vector_type(8)));

__device__ __forceinline__ unsigned short f2bf(float f) {
    unsigned int u = __float_as_uint(f);
    u = (u + 0x7fffu + ((u >> 16) & 1u)) >> 16;
    return (unsigned short)u;
}

__device__ __forceinline__ f32x4 mfma16(bf16x8 a, bf16x8 b, f32x4 c) {
    return __builtin_amdgcn_mfma_f32_16x16x32_bf16(a, b, c, 0, 0, 0);
}

__device__ __forceinline__ void store_c(unsigned short* p, float v) { *p = f2bf(v); }
__device__ __forceinline__ void store_c(float* p, float v) { *p = v; }

// ---------------- cast f32 -> bf16 (vectorized) ----------------
__global__ __launch_bounds__(256) void cast_f32_bf16(const float* __restrict__ in,
                                                     unsigned short* __restrict__ out,
                                                     int n4) {
    int i = blockIdx.x * blockDim.x + threadIdx.x;
    if (i < n4) {
        float4 f = ((const float4*)in)[i];
        ushort4 u;
        u.x = f2bf(f.x); u.y = f2bf(f.y); u.z = f2bf(f.z); u.w = f2bf(f.w);
        ((ushort4*)out)[i] = u;
    }
}

// ---------------- V transpose: v(token,channel) -> vt(bh*128+d, s) ----------------
__global__ __launch_bounds__(256) void transpose_v(const unsigned short* __restrict__ v,
                                                   unsigned short* __restrict__ vt) {
    __shared__ unsigned short t[64][65];
    const int tid = threadIdx.x;
    const int s0 = blockIdx.x * 64;
    const int d0 = blockIdx.y * 64;
    const int bh = blockIdx.z;            // b*16+h
    const int b = bh >> 4, h = bh & 15;

#pragma unroll
    for (int i = 0; i < 2; ++i) {
        int idx = i * 256 + tid;
        int r = idx >> 3, c8 = (idx & 7) * 8;
        ushort8v d = *(const ushort8v*)(v + ((size_t)(b * 2048 + s0 + r)) * 2048 + h * 128 + d0 + c8);
#pragma unroll
        for (int j = 0; j < 8; ++j) t[r][c8 + j] = d[j];
    }
    __syncthreads();
#pragma unroll
    for (int i = 0; i < 2; ++i) {
        int idx = i * 256 + tid;
        int dr = idx >> 3, sc8 = (idx & 7) * 8;
        ushort8v o;
#pragma unroll
        for (int j = 0; j < 8; ++j) o[j] = t[sc8 + j][dr];
        *(ushort8v*)(vt + ((size_t)(bh * 128 + d0 + dr)) * 2048 + s0 + sc8) = o;
    }
}

// ---------------- pipelined GEMM: C = A (MxK) * B^T (B is NxK) ----------------
// BM=256, BN=128, BK=64, 8 waves (4M x 2N), per-wave 64x64 output.
// Ring-3 LDS (144KB), counted vmcnt (6 loads/stage, 2 tiles in flight -> 12/6/0),
// stage-after-second-barrier (race-free), chunk^=(row&7) swizzle (validated 2-way-free).
__device__ __forceinline__ void stage3(const unsigned short* __restrict__ A,
                                       const unsigned short* __restrict__ B,
                                       char* lAslot, char* lBslot,
                                       int row0, int col0, int kt, int K,
                                       int tid, int w) {
#pragma unroll
    for (int j = 0; j < 4; ++j) {          // A: 256 rows x 8 chunks = 2048 chunks
        int ci = j * 512 + tid;
        int r = ci >> 3, p = ci & 7;
        int c = p ^ (r & 7);
        size_t goff = ((size_t)(row0 + r) * K + kt + c * 8) * 2;
        __builtin_amdgcn_global_load_lds(
            (__attribute__((address_space(1))) void*)(void*)((const char*)A + goff),
            (__attribute__((address_space(3))) void*)(lAslot + (j * 512 + w * 64) * 16),
            16, 0, 0);
    }
#pragma unroll
    for (int j = 0; j < 2; ++j) {          // B: 128 rows x 8 chunks = 1024 chunks
        int ci = j * 512 + tid;
        int r = ci >> 3, p = ci & 7;
        int c = p ^ (r & 7);
        size_t goff = ((size_t)(col0 + r) * K + kt + c * 8) * 2;
        __builtin_amdgcn_global_load_lds(
            (__attribute__((address_space(1))) void*)(void*)((const char*)B + goff),
            (__attribute__((address_space(3))) void*)(lBslot + (j * 512 + w * 64) * 16),
            16, 0, 0);
    }
}

template <typename OUT_T>
__global__ __launch_bounds__(512) void gemm_bt3(const unsigned short* __restrict__ A,
                                                const unsigned short* __restrict__ B,
                                                OUT_T* __restrict__ C,
                                                int M, int N, int K) {
    __shared__ __align__(16) unsigned short lA[3][256 * 64];  // 3 x 32KB
    __shared__ __align__(16) unsigned short lB[3][128 * 64];  // 3 x 16KB

    const int tid = threadIdx.x;          // 0..511
    const int w = tid >> 6, lane = tid & 63;
    const int wm = w >> 1, wn = w & 1;    // 4 x 2 wave grid
    const int lane16 = lane & 15, g = lane >> 4;
    const int row0 = blockIdx.y * 256, col0 = blockIdx.x * 128;
    const int NT = K >> 6;                // 32

    f32x4 acc[4][4] = {};

    stage3(A, B, (char*)lA[0], (char*)lB[0], row0, col0, 0,   K, tid, w);
    stage3(A, B, (char*)lA[1], (char*)lB[1], row0, col0, 64,  K, tid, w);
    stage3(A, B, (char*)lA[2], (char*)lB[2], row0, col0, 128, K, tid, w);

    int s = 0;
#pragma unroll 1
    for (int t = 0; t < NT; ++t) {
        if (t + 2 < NT)      asm volatile("s_waitcnt vmcnt(12)" ::: "memory");
        else if (t + 1 < NT) asm volatile("s_waitcnt vmcnt(6)" ::: "memory");
        else                 asm volatile("s_waitcnt vmcnt(0)" ::: "memory");
        __builtin_amdgcn_s_barrier();
        asm volatile("" ::: "memory");

#pragma unroll
        for (int kk = 0; kk < 2; ++kk) {
            bf16x8 aF[4], bF[4];
#pragma unroll
            for (int f = 0; f < 4; ++f) {
                int r = wm * 64 + f * 16 + lane16;
                aF[f] = *(const bf16x8*)&lA[s][r * 64 + ((kk * 4 + g) ^ (r & 7)) * 8];
            }
#pragma unroll
            for (int f = 0; f < 4; ++f) {
                int r = wn * 64 + f * 16 + lane16;
                bF[f] = *(const bf16x8*)&lB[s][r * 64 + ((kk * 4 + g) ^ (r & 7)) * 8];
            }
            __builtin_amdgcn_s_setprio(1);
#pragma unroll
            for (int mf = 0; mf < 4; ++mf)
#pragma unroll
                for (int nf = 0; nf < 4; ++nf)
                    acc[mf][nf] = mfma16(aF[mf], bF[nf], acc[mf][nf]);
            __builtin_amdgcn_s_setprio(0);
        }

        asm volatile("" ::: "memory");
        __builtin_amdgcn_s_barrier();
        asm volatile("" ::: "memory");

        if (t + 3 < NT)
            stage3(A, B, (char*)lA[s], (char*)lB[s], row0, col0, (t + 3) * 64, K, tid, w);
        s = (s == 2) ? 0 : s + 1;
    }

#pragma unroll
    for (int mf = 0; mf < 4; ++mf) {
        int r0 = row0 + wm * 64 + mf * 16 + g * 4;
#pragma unroll
        for (int nf = 0; nf < 4; ++nf) {
            int c = col0 + wn * 64 + nf * 16 + lane16;
#pragma unroll
            for (int r = 0; r < 4; ++r)
                store_c(&C[(size_t)(r0 + r) * N + c], acc[mf][nf][r]);
        }
    }
}

// ---------------- causal flash attention (unchanged from r6 — validated) ----------------
__global__ __launch_bounds__(256) void attn_causal(const unsigned short* __restrict__ Q,
                                                   const unsigned short* __restrict__ K,
                                                   const unsigned short* __restrict__ VT,
                                                   unsigned short* __restrict__ O) {
    __shared__ __align__(16) unsigned short lK[64 * 128];    // swizzled content
    __shared__ __align__(16) unsigned short lVt[128 * 64];   // swizzled content (d-major)
    __shared__ __align__(16) unsigned short lP[4][16 * 80];  // per-wave P tile

    const int tid = threadIdx.x, w = tid >> 6, lane = tid & 63;
    const int lane16 = lane & 15, g = lane >> 4;
    const int bh = blockIdx.y;
    const int b = bh >> 4, h = bh & 15;
    const size_t rowBase = (size_t)b * 2048;  // b*S
    const int hoff = h * 128;
    const float scale = 0.08838834764831845f;  // 1/sqrt(128)

    for (int pass = 0; pass < 2; ++pass) {
        const int qt = pass ? (31 - (int)blockIdx.x) : (int)blockIdx.x;
        const int qt0 = qt * 64;
        const int qr0 = qt0 + w * 16;

        bf16x8 qa[4];
        {
            const unsigned short* qp = Q + (rowBase + qr0 + lane16) * 2048 + hoff;
#pragma unroll
            for (int kk = 0; kk < 4; ++kk)
                qa[kk] = *(const bf16x8*)(qp + kk * 32 + g * 8);
        }

        float m_r[4], l_r[4];
        f32x4 accO[8];
#pragma unroll
        for (int r = 0; r < 4; ++r) { m_r[r] = -1e30f; l_r[r] = 0.f; }
#pragma unroll
        for (int f = 0; f < 8; ++f) accO[f] = f32x4{0.f, 0.f, 0.f, 0.f};

        const int nt = qt + 1;

        for (int t = 0; t < nt; ++t) {
            const int kv0 = t * 64;
            __syncthreads();
#pragma unroll
            for (int i = 0; i < 4; ++i) {
                int ci = (w * 4 + i) * 64 + lane;
                int krow = ci >> 4;
                int kcolb = ((ci & 15) ^ (krow & 7)) * 16;
                size_t goff = ((rowBase + kv0 + krow) * 2048 + hoff) * 2 + kcolb;
                __builtin_amdgcn_global_load_lds(
                    (__attribute__((address_space(1))) void*)(void*)((const char*)K + goff),
                    (__attribute__((address_space(3))) void*)((char*)lK + (w * 4 + i) * 1024),
                    16, 0, 0);
            }
#pragma unroll
            for (int i = 0; i < 4; ++i) {
                int ci = (w * 4 + i) * 64 + lane;
                int drow = ci >> 3;
                int slot = (ci & 7) ^ (drow & 7);
                size_t goff = ((size_t)(bh * 128 + drow) * 2048 + kv0 + slot * 8) * 2;
                __builtin_amdgcn_global_load_lds(
                    (__attribute__((address_space(1))) void*)(void*)((const char*)VT + goff),
                    (__attribute__((address_space(3))) void*)((char*)lVt + (w * 4 + i) * 1024),
                    16, 0, 0);
            }
            __syncthreads();

            float p[4][4];
#pragma unroll
            for (int n = 0; n < 4; ++n) {
                f32x4 sc = {0.f, 0.f, 0.f, 0.f};
                int row = n * 16 + lane16;
#pragma unroll
                for (int kk = 0; kk < 4; ++kk) {
                    int sw = (kk * 4 + g) ^ (row & 7);
                    bf16x8 kb = *(const bf16x8*)&lK[row * 128 + sw * 8];
                    sc = mfma16(qa[kk], kb, sc);
                }
#pragma unroll
                for (int r = 0; r < 4; ++r) p[n][r] = sc[r] * scale;
            }
            if (t == nt - 1) {
#pragma unroll
                for (int n = 0; n < 4; ++n)
#pragma unroll
                    for (int r = 0; r < 4; ++r) {
                        int qi = qr0 + g * 4 + r, ki = kv0 + n * 16 + lane16;
                        if (ki > qi) p[n][r] = -1e30f;
                    }
            }
#pragma unroll
            for (int r = 0; r < 4; ++r) {
                float rm = fmaxf(fmaxf(p[0][r], p[1][r]), fmaxf(p[2][r], p[3][r]));
#pragma unroll
                for (int off = 1; off < 16; off <<= 1)
                    rm = fmaxf(rm, __shfl_xor(rm, off, 64));
                float mn = fmaxf(m_r[r], rm);
                float fac = __expf(m_r[r] - mn);
                float rs = 0.f;
#pragma unroll
                for (int n = 0; n < 4; ++n) { p[n][r] = __expf(p[n][r] - mn); rs += p[n][r]; }
#pragma unroll
                for (int off = 1; off < 16; off <<= 1)
                    rs += __shfl_xor(rs, off, 64);
                l_r[r] = l_r[r] * fac + rs;
                m_r[r] = mn;
#pragma unroll
                for (int f = 0; f < 8; ++f) accO[f][r] *= fac;
            }
#pragma unroll
            for (int n = 0; n < 4; ++n)
#pragma unroll
                for (int r = 0; r < 4; ++r)
                    lP[w][(g * 4 + r) * 80 + n * 16 + lane16] = f2bf(p[n][r]);
            asm volatile("s_waitcnt lgkmcnt(0)" ::: "memory");
#pragma unroll
            for (int kk2 = 0; kk2 < 2; ++kk2) {
                bf16x8 pa = *(const bf16x8*)&lP[w][lane16 * 80 + kk2 * 32 + g * 8];
#pragma unroll
                for (int f = 0; f < 8; ++f) {
                    int row = f * 16 + lane16;
                    int slot = (kk2 * 4 + g) ^ (row & 7);
                    bf16x8 vb = *(const bf16x8*)&lVt[row * 64 + slot * 8];
                    accO[f] = mfma16(pa, vb, accO[f]);
                }
            }
        }

#pragma unroll
        for (int f = 0; f < 8; ++f)
#pragma unroll
            for (int r = 0; r < 4; ++r) {
                float ov = accO[f][r] / l_r[r];
                O[(rowBase + qr0 + g * 4 + r) * 2048 + hoff + f * 16 + lane16] = f2bf(ov);
            }
    }
}

// ---------------- launch ----------------
extern "C" void kernel_launch(void* const* d_in, const int* in_sizes, int n_in,
                              void* d_out, int out_size, void* d_ws, size_t ws_size,
                              hipStream_t stream) {
    const float* x  = (const float*)d_in[0];
    // d_in[1] = causal mask (static triu(k=1)) — applied analytically
    const float* Wq = (const float*)d_in[2];
    const float* Wk = (const float*)d_in[3];
    const float* Wv = (const float*)d_in[4];
    const float* Wo = (const float*)d_in[5];
    float* out = (float*)d_out;

    char* ws = (char*)d_ws;
    unsigned short* xb = (unsigned short*)(ws);                    // 16MB; x bf16, later vt
    unsigned short* q  = (unsigned short*)(ws + (size_t)(16u << 20));
    unsigned short* k  = (unsigned short*)(ws + (size_t)(32u << 20));
    unsigned short* v  = (unsigned short*)(ws + (size_t)(48u << 20)); // v bf16, later attn O
    unsigned short* wb = (unsigned short*)(ws + (size_t)(64u << 20)); // 8MB weight buf
    unsigned short* vt = xb;   // vt reuses xb region (x dead after QKV gemms)
    unsigned short* o  = v;    // attn output reuses v region (v dead after transpose)

    const int M = 4096, D = 2048;
    dim3 gg(D / 128, M / 256);  // (16, 16) = 256 blocks, uniform

    cast_f32_bf16<<<(M * D / 4) / 256, 256, 0, stream>>>(x, xb, M * D / 4);

    cast_f32_bf16<<<(D * D / 4) / 256, 256, 0, stream>>>(Wq, wb, D * D / 4);
    gemm_bt3<unsigned short><<<gg, 512, 0, stream>>>(xb, wb, q, M, D, D);
    cast_f32_bf16<<<(D * D / 4) / 256, 256, 0, stream>>>(Wk, wb, D * D / 4);
    gemm_bt3<unsigned short><<<gg, 512, 0, stream>>>(xb, wb, k, M, D, D);
    cast_f32_bf16<<<(D * D / 4) / 256, 256, 0, stream>>>(Wv, wb, D * D / 4);
    gemm_bt3<unsigned short><<<gg, 512, 0, stream>>>(xb, wb, v, M, D, D);

    transpose_v<<<dim3(32, 2, 32), 256, 0, stream>>>(v, vt);

    attn_causal<<<dim3(16, 32), 256, 0, stream>>>(q, k, vt, o);

    cast_f32_bf16<<<(D * D / 4) / 256, 256, 0, stream>>>(Wo, wb, D * D / 4);
    gemm_bt3<float><<<gg, 512, 0, stream>>>(o, wb, out, M, D, D);
}

// Round 11
// 431.450 us; speedup vs baseline: 1.1306x; 1.0329x over previous
//
#include <hip/hip_runtime.h>
#include <hip/hip_bf16.h>

typedef __bf16 bf16x8 __attribute__((ext_vector_type(8)));
typedef float f32x4 __attribute__((ext_vector_type(4)));
typedef unsigned short ushort8v __attribute__((ext_vector_type(8)));

__device__ __forceinline__ unsigned short f2bf(float f) {
    unsigned int u = __float_as_uint(f);
    u = (u + 0x7fffu + ((u >> 16) & 1u)) >> 16;
    return (unsigned short)u;
}

__device__ __forceinline__ f32x4 mfma16(bf16x8 a, bf16x8 b, f32x4 c) {
    return __builtin_amdgcn_mfma_f32_16x16x32_bf16(a, b, c, 0, 0, 0);
}

__device__ __forceinline__ void store_c(unsigned short* p, float v) { *p = f2bf(v); }
__device__ __forceinline__ void store_c(float* p, float v) { *p = v; }

// ---------------- cast f32 -> bf16 (vectorized) ----------------
__global__ __launch_bounds__(256) void cast_f32_bf16(const float* __restrict__ in,
                                                     unsigned short* __restrict__ out,
                                                     int n4) {
    int i = blockIdx.x * blockDim.x + threadIdx.x;
    if (i < n4) {
        float4 f = ((const float4*)in)[i];
        ushort4 u;
        u.x = f2bf(f.x); u.y = f2bf(f.y); u.z = f2bf(f.z); u.w = f2bf(f.w);
        ((ushort4*)out)[i] = u;
    }
}

// ---------------- V transpose: v(token,channel) -> vt(bh*128+d, s) ----------------
__global__ __launch_bounds__(256) void transpose_v(const unsigned short* __restrict__ v,
                                                   unsigned short* __restrict__ vt) {
    __shared__ unsigned short t[64][65];
    const int tid = threadIdx.x;
    const int s0 = blockIdx.x * 64;
    const int d0 = blockIdx.y * 64;
    const int bh = blockIdx.z;            // b*16+h
    const int b = bh >> 4, h = bh & 15;

#pragma unroll
    for (int i = 0; i < 2; ++i) {
        int idx = i * 256 + tid;
        int r = idx >> 3, c8 = (idx & 7) * 8;
        ushort8v d = *(const ushort8v*)(v + ((size_t)(b * 2048 + s0 + r)) * 2048 + h * 128 + d0 + c8);
#pragma unroll
        for (int j = 0; j < 8; ++j) t[r][c8 + j] = d[j];
    }
    __syncthreads();
#pragma unroll
    for (int i = 0; i < 2; ++i) {
        int idx = i * 256 + tid;
        int dr = idx >> 3, sc8 = (idx & 7) * 8;
        ushort8v o;
#pragma unroll
        for (int j = 0; j < 8; ++j) o[j] = t[sc8 + j][dr];
        *(ushort8v*)(vt + ((size_t)(bh * 128 + d0 + dr)) * 2048 + s0 + sc8) = o;
    }
}

// ---------------- gemm_bt3 (proven, used for V and O projections) ----------------
__device__ __forceinline__ void stage3(const unsigned short* __restrict__ A,
                                       const unsigned short* __restrict__ B,
                                       char* lAslot, char* lBslot,
                                       int row0, int col0, int kt, int K,
                                       int tid, int w) {
#pragma unroll
    for (int j = 0; j < 4; ++j) {
        int ci = j * 512 + tid;
        int r = ci >> 3, p = ci & 7;
        int c = p ^ (r & 7);
        size_t goff = ((size_t)(row0 + r) * K + kt + c * 8) * 2;
        __builtin_amdgcn_global_load_lds(
            (__attribute__((address_space(1))) void*)(void*)((const char*)A + goff),
            (__attribute__((address_space(3))) void*)(lAslot + (j * 512 + w * 64) * 16),
            16, 0, 0);
    }
#pragma unroll
    for (int j = 0; j < 2; ++j) {
        int ci = j * 512 + tid;
        int r = ci >> 3, p = ci & 7;
        int c = p ^ (r & 7);
        size_t goff = ((size_t)(col0 + r) * K + kt + c * 8) * 2;
        __builtin_amdgcn_global_load_lds(
            (__attribute__((address_space(1))) void*)(void*)((const char*)B + goff),
            (__attribute__((address_space(3))) void*)(lBslot + (j * 512 + w * 64) * 16),
            16, 0, 0);
    }
}

template <typename OUT_T>
__global__ __launch_bounds__(512) void gemm_bt3(const unsigned short* __restrict__ A,
                                                const unsigned short* __restrict__ B,
                                                OUT_T* __restrict__ C,
                                                int M, int N, int K) {
    __shared__ __align__(16) unsigned short lA[3][256 * 64];
    __shared__ __align__(16) unsigned short lB[3][128 * 64];

    const int tid = threadIdx.x;
    const int w = tid >> 6, lane = tid & 63;
    const int wm = w >> 1, wn = w & 1;
    const int lane16 = lane & 15, g = lane >> 4;
    const int row0 = blockIdx.y * 256, col0 = blockIdx.x * 128;
    const int NT = K >> 6;

    f32x4 acc[4][4] = {};

    stage3(A, B, (char*)lA[0], (char*)lB[0], row0, col0, 0,   K, tid, w);
    stage3(A, B, (char*)lA[1], (char*)lB[1], row0, col0, 64,  K, tid, w);
    stage3(A, B, (char*)lA[2], (char*)lB[2], row0, col0, 128, K, tid, w);

    int s = 0;
#pragma unroll 1
    for (int t = 0; t < NT; ++t) {
        if (t + 2 < NT)      asm volatile("s_waitcnt vmcnt(12)" ::: "memory");
        else if (t + 1 < NT) asm volatile("s_waitcnt vmcnt(6)" ::: "memory");
        else                 asm volatile("s_waitcnt vmcnt(0)" ::: "memory");
        __builtin_amdgcn_s_barrier();
        asm volatile("" ::: "memory");

#pragma unroll
        for (int kk = 0; kk < 2; ++kk) {
            bf16x8 aF[4], bF[4];
#pragma unroll
            for (int f = 0; f < 4; ++f) {
                int r = wm * 64 + f * 16 + lane16;
                aF[f] = *(const bf16x8*)&lA[s][r * 64 + ((kk * 4 + g) ^ (r & 7)) * 8];
            }
#pragma unroll
            for (int f = 0; f < 4; ++f) {
                int r = wn * 64 + f * 16 + lane16;
                bF[f] = *(const bf16x8*)&lB[s][r * 64 + ((kk * 4 + g) ^ (r & 7)) * 8];
            }
            __builtin_amdgcn_s_setprio(1);
#pragma unroll
            for (int mf = 0; mf < 4; ++mf)
#pragma unroll
                for (int nf = 0; nf < 4; ++nf)
                    acc[mf][nf] = mfma16(aF[mf], bF[nf], acc[mf][nf]);
            __builtin_amdgcn_s_setprio(0);
        }

        asm volatile("" ::: "memory");
        __builtin_amdgcn_s_barrier();
        asm volatile("" ::: "memory");

        if (t + 3 < NT)
            stage3(A, B, (char*)lA[s], (char*)lB[s], row0, col0, (t + 3) * 64, K, tid, w);
        s = (s == 2) ? 0 : s + 1;
    }

#pragma unroll
    for (int mf = 0; mf < 4; ++mf) {
        int r0 = row0 + wm * 64 + mf * 16 + g * 4;
#pragma unroll
        for (int nf = 0; nf < 4; ++nf) {
            int c = col0 + wn * 64 + nf * 16 + lane16;
#pragma unroll
            for (int r = 0; r < 4; ++r)
                store_c(&C[(size_t)(r0 + r) * N + c], acc[mf][nf][r]);
        }
    }
}

// ---------------- gemm_qk: fused Q+K projection ----------------
// A (4096x2048) x wqk^T (wqk = 4096x2048: rows 0-2047 Wq, 2048-4095 Wk).
// BM=256, BN=256, BK=64, 8 waves (2M x 4N), per-wave 128x64, ring-2 LDS 128KB,
// counted vmcnt(8)/0, block routes output: bx<8 -> Cq, else Ck.
__device__ __forceinline__ void stage4(const unsigned short* __restrict__ A,
                                       const unsigned short* __restrict__ B,
                                       char* lAslot, char* lBslot,
                                       int row0, int bcol0, int kt, int K,
                                       int tid, int w) {
#pragma unroll
    for (int j = 0; j < 4; ++j) {          // A: 256 rows x 8 chunks
        int ci = j * 512 + tid;
        int r = ci >> 3, p = ci & 7;
        int c = p ^ (r & 7);
        size_t goff = ((size_t)(row0 + r) * K + kt + c * 8) * 2;
        __builtin_amdgcn_global_load_lds(
            (__attribute__((address_space(1))) void*)(void*)((const char*)A + goff),
            (__attribute__((address_space(3))) void*)(lAslot + (j * 512 + w * 64) * 16),
            16, 0, 0);
    }
#pragma unroll
    for (int j = 0; j < 4; ++j) {          // B: 256 rows x 8 chunks
        int ci = j * 512 + tid;
        int r = ci >> 3, p = ci & 7;
        int c = p ^ (r & 7);
        size_t goff = ((size_t)(bcol0 + r) * K + kt + c * 8) * 2;
        __builtin_amdgcn_global_load_lds(
            (__attribute__((address_space(1))) void*)(void*)((const char*)B + goff),
            (__attribute__((address_space(3))) void*)(lBslot + (j * 512 + w * 64) * 16),
            16, 0, 0);
    }
}

__global__ __launch_bounds__(512) void gemm_qk(const unsigned short* __restrict__ A,
                                               const unsigned short* __restrict__ B,
                                               unsigned short* __restrict__ Cq,
                                               unsigned short* __restrict__ Ck,
                                               int M, int K) {
    __shared__ __align__(16) unsigned short lA[2][256 * 64];  // 2 x 32KB
    __shared__ __align__(16) unsigned short lB[2][256 * 64];  // 2 x 32KB

    const int tid = threadIdx.x;
    const int w = tid >> 6, lane = tid & 63;
    const int wm = w >> 2, wn = w & 3;    // 2M x 4N waves, per-wave 128x64
    const int lane16 = lane & 15, g = lane >> 4;
    const int bx = blockIdx.x;            // 0..15 (cols 0..4095)
    const int row0 = blockIdx.y * 256;
    const int bcol0 = bx * 256;
    unsigned short* Cout = (bx < 8) ? Cq : Ck;
    const int col0 = bcol0 & 2047;
    const int NT = K >> 6;                // 32

    f32x4 acc[8][4] = {};

    stage4(A, B, (char*)lA[0], (char*)lB[0], row0, bcol0, 0,  K, tid, w);
    stage4(A, B, (char*)lA[1], (char*)lB[1], row0, bcol0, 64, K, tid, w);

#pragma unroll 1
    for (int t = 0; t < NT; ++t) {
        const int s = t & 1;
        if (t + 1 < NT) asm volatile("s_waitcnt vmcnt(8)" ::: "memory");
        else            asm volatile("s_waitcnt vmcnt(0)" ::: "memory");
        __builtin_amdgcn_s_barrier();
        asm volatile("" ::: "memory");

#pragma unroll
        for (int kk = 0; kk < 2; ++kk) {
            bf16x8 aF[8], bF[4];
#pragma unroll
            for (int f = 0; f < 8; ++f) {
                int r = wm * 128 + f * 16 + lane16;
                aF[f] = *(const bf16x8*)&lA[s][r * 64 + ((kk * 4 + g) ^ (r & 7)) * 8];
            }
#pragma unroll
            for (int f = 0; f < 4; ++f) {
                int r = wn * 64 + f * 16 + lane16;
                bF[f] = *(const bf16x8*)&lB[s][r * 64 + ((kk * 4 + g) ^ (r & 7)) * 8];
            }
            __builtin_amdgcn_s_setprio(1);
#pragma unroll
            for (int mf = 0; mf < 8; ++mf)
#pragma unroll
                for (int nf = 0; nf < 4; ++nf)
                    acc[mf][nf] = mfma16(aF[mf], bF[nf], acc[mf][nf]);
            __builtin_amdgcn_s_setprio(0);
        }

        asm volatile("" ::: "memory");
        __builtin_amdgcn_s_barrier();
        asm volatile("" ::: "memory");

        if (t + 2 < NT)
            stage4(A, B, (char*)lA[s], (char*)lB[s], row0, bcol0, (t + 2) * 64, K, tid, w);
    }

#pragma unroll
    for (int mf = 0; mf < 8; ++mf) {
        int r0 = row0 + wm * 128 + mf * 16 + g * 4;
#pragma unroll
        for (int nf = 0; nf < 4; ++nf) {
            int c = col0 + wn * 64 + nf * 16 + lane16;
#pragma unroll
            for (int r = 0; r < 4; ++r)
                store_c(&Cout[(size_t)(r0 + r) * 2048 + c], acc[mf][nf][r]);
        }
    }
}

// ---------------- causal flash attention: QBLK=128 (8 waves), KVBLK=64 ----------------
// Work-balanced: block bx handles q-tile bx then 15-bx (34 KV tiles each).
// lK and lVt chunk-XOR-swizzled via pre-swizzled global_load_lds source (validated r6).
__global__ __launch_bounds__(512) void attn_causal(const unsigned short* __restrict__ Q,
                                                   const unsigned short* __restrict__ K,
                                                   const unsigned short* __restrict__ VT,
                                                   unsigned short* __restrict__ O) {
    __shared__ __align__(16) unsigned short lK[64 * 128];
    __shared__ __align__(16) unsigned short lVt[128 * 64];
    __shared__ __align__(16) unsigned short lP[8][16 * 80];

    const int tid = threadIdx.x, w = tid >> 6, lane = tid & 63;
    const int lane16 = lane & 15, g = lane >> 4;
    const int bh = blockIdx.y;
    const int b = bh >> 4, h = bh & 15;
    const size_t rowBase = (size_t)b * 2048;
    const int hoff = h * 128;
    const float scale = 0.08838834764831845f;  // 1/sqrt(128)

    for (int pass = 0; pass < 2; ++pass) {
        const int qt = pass ? (15 - (int)blockIdx.x) : (int)blockIdx.x;
        const int qt0 = qt * 128;
        const int qr0 = qt0 + w * 16;

        bf16x8 qa[4];
        {
            const unsigned short* qp = Q + (rowBase + qr0 + lane16) * 2048 + hoff;
#pragma unroll
            for (int kk = 0; kk < 4; ++kk)
                qa[kk] = *(const bf16x8*)(qp + kk * 32 + g * 8);
        }

        float m_r[4], l_r[4];
        f32x4 accO[8];
#pragma unroll
        for (int r = 0; r < 4; ++r) { m_r[r] = -1e30f; l_r[r] = 0.f; }
#pragma unroll
        for (int f = 0; f < 8; ++f) accO[f] = f32x4{0.f, 0.f, 0.f, 0.f};

        const int nt = 2 * (qt + 1);

        for (int t = 0; t < nt; ++t) {
            const int kv0 = t * 64;
            __syncthreads();
            // stage K tile (64 x 128): 2 chunks/thread, chunk-XOR swizzled source
#pragma unroll
            for (int i = 0; i < 2; ++i) {
                int ci = i * 512 + w * 64 + lane;
                int krow = ci >> 4;
                int kcolb = ((ci & 15) ^ (krow & 7)) * 16;
                size_t goff = ((rowBase + kv0 + krow) * 2048 + hoff) * 2 + kcolb;
                __builtin_amdgcn_global_load_lds(
                    (__attribute__((address_space(1))) void*)(void*)((const char*)K + goff),
                    (__attribute__((address_space(3))) void*)((char*)lK + (i * 512 + w * 64) * 16),
                    16, 0, 0);
            }
            // stage Vt tile (128 d-rows x 64 kv): 2 chunks/thread
#pragma unroll
            for (int i = 0; i < 2; ++i) {
                int ci = i * 512 + w * 64 + lane;
                int drow = ci >> 3;
                int slot = (ci & 7) ^ (drow & 7);
                size_t goff = ((size_t)(bh * 128 + drow) * 2048 + kv0 + slot * 8) * 2;
                __builtin_amdgcn_global_load_lds(
                    (__attribute__((address_space(1))) void*)(void*)((const char*)VT + goff),
                    (__attribute__((address_space(3))) void*)((char*)lVt + (i * 512 + w * 64) * 16),
                    16, 0, 0);
            }
            __syncthreads();

            float p[4][4];
#pragma unroll
            for (int n = 0; n < 4; ++n) {
                f32x4 sc = {0.f, 0.f, 0.f, 0.f};
                int row = n * 16 + lane16;
#pragma unroll
                for (int kk = 0; kk < 4; ++kk) {
                    int sw = (kk * 4 + g) ^ (row & 7);
                    bf16x8 kb = *(const bf16x8*)&lK[row * 128 + sw * 8];
                    sc = mfma16(qa[kk], kb, sc);
                }
#pragma unroll
                for (int r = 0; r < 4; ++r) p[n][r] = sc[r] * scale;
            }
            if (t >= nt - 2) {  // diagonal 128x128 block spans the last two KV tiles
#pragma unroll
                for (int n = 0; n < 4; ++n)
#pragma unroll
                    for (int r = 0; r < 4; ++r) {
                        int qi = qr0 + g * 4 + r, ki = kv0 + n * 16 + lane16;
                        if (ki > qi) p[n][r] = -1e30f;
                    }
            }
#pragma unroll
            for (int r = 0; r < 4; ++r) {
                float rm = fmaxf(fmaxf(p[0][r], p[1][r]), fmaxf(p[2][r], p[3][r]));
#pragma unroll
                for (int off = 1; off < 16; off <<= 1)
                    rm = fmaxf(rm, __shfl_xor(rm, off, 64));
                float mn = fmaxf(m_r[r], rm);
                float fac = __expf(m_r[r] - mn);
                float rs = 0.f;
#pragma unroll
                for (int n = 0; n < 4; ++n) { p[n][r] = __expf(p[n][r] - mn); rs += p[n][r]; }
#pragma unroll
                for (int off = 1; off < 16; off <<= 1)
                    rs += __shfl_xor(rs, off, 64);
                l_r[r] = l_r[r] * fac + rs;
                m_r[r] = mn;
#pragma unroll
                for (int f = 0; f < 8; ++f) accO[f][r] *= fac;
            }
#pragma unroll
            for (int n = 0; n < 4; ++n)
#pragma unroll
                for (int r = 0; r < 4; ++r)
                    lP[w][(g * 4 + r) * 80 + n * 16 + lane16] = f2bf(p[n][r]);
            asm volatile("s_waitcnt lgkmcnt(0)" ::: "memory");
#pragma unroll
            for (int kk2 = 0; kk2 < 2; ++kk2) {
                bf16x8 pa = *(const bf16x8*)&lP[w][lane16 * 80 + kk2 * 32 + g * 8];
#pragma unroll
                for (int f = 0; f < 8; ++f) {
                    int row = f * 16 + lane16;
                    int slot = (kk2 * 4 + g) ^ (row & 7);
                    bf16x8 vb = *(const bf16x8*)&lVt[row * 64 + slot * 8];
                    accO[f] = mfma16(pa, vb, accO[f]);
                }
            }
        }

#pragma unroll
        for (int f = 0; f < 8; ++f)
#pragma unroll
            for (int r = 0; r < 4; ++r) {
                float ov = accO[f][r] / l_r[r];
                O[(rowBase + qr0 + g * 4 + r) * 2048 + hoff + f * 16 + lane16] = f2bf(ov);
            }
    }
}

// ---------------- launch ----------------
extern "C" void kernel_launch(void* const* d_in, const int* in_sizes, int n_in,
                              void* d_out, int out_size, void* d_ws, size_t ws_size,
                              hipStream_t stream) {
    const float* x  = (const float*)d_in[0];
    // d_in[1] = causal mask (static triu(k=1)) — applied analytically
    const float* Wq = (const float*)d_in[2];
    const float* Wk = (const float*)d_in[3];
    const float* Wv = (const float*)d_in[4];
    const float* Wo = (const float*)d_in[5];
    float* out = (float*)d_out;

    char* ws = (char*)d_ws;
    // [0,16M)  xb (x bf16)            -> vt after QKV gemms
    // [16,32M) q
    // [32,48M) k
    // [48,64M) wqk (Wq|Wk bf16)       -> v after V-gemm -> attn O after transpose
    // [64,72M) wb (Wv, then Wo)
    unsigned short* xb  = (unsigned short*)(ws);
    unsigned short* q   = (unsigned short*)(ws + (size_t)(16u << 20));
    unsigned short* k   = (unsigned short*)(ws + (size_t)(32u << 20));
    unsigned short* wqk = (unsigned short*)(ws + (size_t)(48u << 20));
    unsigned short* wb  = (unsigned short*)(ws + (size_t)(64u << 20));
    unsigned short* v   = wqk;  // v overwrites wqk (dead after QK gemm)
    unsigned short* vt  = xb;   // vt overwrites xb (dead after V gemm)
    unsigned short* o   = v;    // attn output overwrites v (dead after transpose)

    const int M = 4096, D = 2048;

    cast_f32_bf16<<<(M * D / 4) / 256, 256, 0, stream>>>(x, xb, M * D / 4);

    // fused Q+K projection: wqk = [Wq; Wk] (4096 x 2048)
    cast_f32_bf16<<<(D * D / 4) / 256, 256, 0, stream>>>(Wq, wqk, D * D / 4);
    cast_f32_bf16<<<(D * D / 4) / 256, 256, 0, stream>>>(Wk, wqk + (size_t)D * D, D * D / 4);
    gemm_qk<<<dim3(16, 16), 512, 0, stream>>>(xb, wqk, q, k, M, D);

    // V projection (proven bt3, full grid)
    cast_f32_bf16<<<(D * D / 4) / 256, 256, 0, stream>>>(Wv, wb, D * D / 4);
    gemm_bt3<unsigned short><<<dim3(16, 16), 512, 0, stream>>>(xb, wb, v, M, D, D);

    transpose_v<<<dim3(32, 2, 32), 256, 0, stream>>>(v, vt);

    attn_causal<<<dim3(8, 32), 512, 0, stream>>>(q, k, vt, o);

    cast_f32_bf16<<<(D * D / 4) / 256, 256, 0, stream>>>(Wo, wb, D * D / 4);
    gemm_bt3<float><<<dim3(16, 16), 512, 0, stream>>>(o, wb, out, M, D, D);
}